// Round 16
// baseline (213.391 us; speedup 1.0000x reference)
//
#include <hip/hip_runtime.h>
#include <hip/hip_bf16.h>
#include <cstdint>

#define B_ 2
#define S_ 2048
#define D_ 1024
#define H_ 16
#define HD_ 64

#define SCALE_LOG2 0.18033688011112042f   // (1/8) * log2(e), folded into wq cast

typedef __attribute__((ext_vector_type(8))) __bf16 bf16x8;
typedef __attribute__((ext_vector_type(8))) unsigned short ushort8;
typedef __attribute__((ext_vector_type(4))) unsigned short ushort4v;
typedef __attribute__((ext_vector_type(4))) float f32x4;

__device__ __forceinline__ unsigned short f2bf(float f) {
  __bf16 h = (__bf16)f;                       // native v_cvt (RNE)
  return __builtin_bit_cast(unsigned short, h);
}

__device__ __forceinline__ float bf2f(unsigned short u) {
  union { unsigned int i; float f; } v; v.i = ((unsigned int)u) << 16; return v.f;
}

__device__ __forceinline__ float fexp2(float x) {
#if __has_builtin(__builtin_amdgcn_exp2f)
  return __builtin_amdgcn_exp2f(x);           // raw v_exp_f32
#else
  return exp2f(x);
#endif
}

__device__ __forceinline__ f32x4 mfma16(bf16x8 a, bf16x8 b, f32x4 c) {
  return __builtin_amdgcn_mfma_f32_16x16x32_bf16(a, b, c, 0, 0, 0);
}

// async global->LDS DMA, 16B per lane: LDS dest = wave-uniform base + lane*16
__device__ __forceinline__ void gload16(const unsigned short* g, unsigned short* l) {
  __builtin_amdgcn_global_load_lds(
      (const __attribute__((address_space(1))) unsigned int*)g,
      (__attribute__((address_space(3))) unsigned int*)l, 16, 0, 0);
}

// LDS-hazard-only barrier: does NOT drain vmcnt (attn kernel only).
#define LGKM_BARRIER()                                        \
  do {                                                        \
    asm volatile("s_waitcnt lgkmcnt(0)" ::: "memory");        \
    __builtin_amdgcn_s_barrier();                             \
  } while (0)

// 32B-granule XOR swizzle for [64][64]-short LDS tiles (keeps 16B alignment).
#define SWZ(r, sc) ((sc) ^ (((r) & 3) << 4))

// ---------------------------------------------------------------------------
// Kernel 0: f32 -> bf16 pre-cast. q,k,v,wq(*scale),wk,wv -> scratch (in the
// attn region of d_out -- dead until the attn kernel overwrites it); wo -> ws.
// ---------------------------------------------------------------------------
__global__ __launch_bounds__(256) void cast_kernel(
    const float* __restrict__ q, const float* __restrict__ k,
    const float* __restrict__ v, const float* __restrict__ wq,
    const float* __restrict__ wk, const float* __restrict__ wv,
    const float* __restrict__ wo,
    unsigned short* __restrict__ xq, unsigned short* __restrict__ xk,
    unsigned short* __restrict__ xv, unsigned short* __restrict__ wqb,
    unsigned short* __restrict__ wkb, unsigned short* __restrict__ wvb,
    unsigned short* __restrict__ wob)
{
  const size_t M4 = (size_t)4 << 20, M1 = (size_t)1 << 20;
  size_t i = ((size_t)blockIdx.x * 256 + threadIdx.x) * 8;
  const float* src; unsigned short* dst; float sc = 1.f; size_t off;
  if (i < M4)                 { src = q;  dst = xq;  off = i; }
  else if (i < 2 * M4)        { src = k;  dst = xk;  off = i - M4; }
  else if (i < 3 * M4)        { src = v;  dst = xv;  off = i - 2 * M4; }
  else if (i < 3 * M4 + M1)   { src = wq; dst = wqb; off = i - 3 * M4; sc = SCALE_LOG2; }
  else if (i < 3 * M4 + 2*M1) { src = wk; dst = wkb; off = i - 3 * M4 - M1; }
  else if (i < 3 * M4 + 3*M1) { src = wv; dst = wvb; off = i - 3 * M4 - 2 * M1; }
  else                        { src = wo; dst = wob; off = i - 3 * M4 - 3 * M1; }
  f32x4 a = *(const f32x4*)(src + off);
  f32x4 b = *(const f32x4*)(src + off + 4);
  ushort8 o;
#pragma unroll
  for (int r = 0; r < 4; ++r) { o[r] = f2bf(a[r] * sc); o[4 + r] = f2bf(b[r] * sc); }
  *(ushort8*)(dst + off) = o;
}

// ---------------------------------------------------------------------------
// Kernel A: QKV projections, bf16 NT GEMM with global_load_lds (m97 recipe).
// ---------------------------------------------------------------------------
__global__ __launch_bounds__(256) void proj_qkv_kernel(
    const unsigned short* __restrict__ xq, const unsigned short* __restrict__ xk,
    const unsigned short* __restrict__ xv, const unsigned short* __restrict__ wqb,
    const unsigned short* __restrict__ wkb, const unsigned short* __restrict__ wvb,
    unsigned short* __restrict__ qh, unsigned short* __restrict__ kh,
    unsigned short* __restrict__ vt)
{
  __shared__ unsigned short As[128 * 32];   // linear, row = 32 bf16 (64B)
  __shared__ unsigned short Bs[128 * 32];

  const int z = blockIdx.z;
  const unsigned short* X = (z == 0) ? xq : (z == 1) ? xk : xv;
  const unsigned short* W = (z == 0) ? wqb : (z == 1) ? wkb : wvb;
  unsigned short* dst = (z == 0) ? qh : (z == 1) ? kh : vt;

  const int lin = blockIdx.x + 8 * blockIdx.y;
  const int swz = (lin & 7) * 32 + (lin >> 3);
  const int bx = swz & 7, by = swz >> 3;

  const int tid = threadIdx.x;
  const int lane = tid & 63, w = tid >> 6;
  const int c = lane & 15, g = lane >> 4;
  const int wr = w >> 1, wc = w & 1;               // 2x2 waves, 64x64 each
  const int m0 = by * 128, n0 = bx * 128;

  const int arow = 2 * w * 16 + (lane >> 2);
  const int cs = (lane & 3) ^ ((lane >> 2) & 3);   // inverse-permuted src slot
  const unsigned short* Asrc0 = X + (size_t)(m0 + arow) * D_ + cs * 8;
  const unsigned short* Asrc1 = Asrc0 + (size_t)16 * D_;
  const unsigned short* Bsrc0 = W + (size_t)(n0 + arow) * D_ + cs * 8;
  const unsigned short* Bsrc1 = Bsrc0 + (size_t)16 * D_;
  unsigned short* Adst0 = &As[(2 * w) * 16 * 32];
  unsigned short* Adst1 = &As[(2 * w + 1) * 16 * 32];
  unsigned short* Bdst0 = &Bs[(2 * w) * 16 * 32];
  unsigned short* Bdst1 = &Bs[(2 * w + 1) * 16 * 32];

  f32x4 acc[4][4];
#pragma unroll
  for (int i = 0; i < 4; ++i)
#pragma unroll
    for (int j = 0; j < 4; ++j) acc[i][j] = (f32x4){0.f, 0.f, 0.f, 0.f};

  for (int kt = 0; kt < 32; ++kt) {
    gload16(Asrc0 + kt * 32, Adst0);
    gload16(Asrc1 + kt * 32, Adst1);
    gload16(Bsrc0 + kt * 32, Bdst0);
    gload16(Bsrc1 + kt * 32, Bdst1);
    __syncthreads();

    bf16x8 af[4], bfr[4];
#pragma unroll
    for (int i = 0; i < 4; ++i) {
      const int row = wr * 64 + i * 16 + c;
      af[i] = *(bf16x8*)&As[row * 32 + 8 * (g ^ (c & 3))];
    }
#pragma unroll
    for (int i = 0; i < 4; ++i) {
      const int row = wc * 64 + i * 16 + c;
      bfr[i] = *(bf16x8*)&Bs[row * 32 + 8 * (g ^ (c & 3))];
    }
#pragma unroll
    for (int mi = 0; mi < 4; ++mi)
#pragma unroll
      for (int ni = 0; ni < 4; ++ni)
        acc[mi][ni] = mfma16(af[mi], bfr[ni], acc[mi][ni]);
    __syncthreads();
  }

#pragma unroll
  for (int mi = 0; mi < 4; ++mi) {
#pragma unroll
    for (int ni = 0; ni < 4; ++ni) {
      const int n = n0 + wc * 64 + ni * 16 + c;
      const int h = n >> 6, hd = n & 63;
      if (z < 2) {
#pragma unroll
        for (int r = 0; r < 4; ++r) {
          const int m = m0 + wr * 64 + mi * 16 + g * 4 + r;
          const int b = m >> 11, s = m & 2047;
          dst[((size_t)(b * H_ + h) * S_ + s) * HD_ + hd] = f2bf(acc[mi][ni][r]);
        }
      } else {
        const int m = m0 + wr * 64 + mi * 16 + g * 4;
        const int b = m >> 11, s = m & 2047;
        ushort4v pk;
#pragma unroll
        for (int r = 0; r < 4; ++r) pk[r] = f2bf(acc[mi][ni][r]);
        *(ushort4v*)&dst[((size_t)(b * H_ + h) * HD_ + hd) * S_ + s] = pk;
      }
    }
  }
}

// ---------------------------------------------------------------------------
// Kernel B: attention = R14 3-sweep A/B fusion + DOUBLE-BUFFERED K/V with ONE
// lgkm-only barrier per k-tile (barriers 192 -> 96 per block).
// Hazard: wave X's ds_write buf[p] at tile k is ordered after barrier k-1,
// which wave Y reaches only after computing tile k-2 (same buffer) with
// lgkmcnt drained. Prefetch loads issue between ds_write and barrier ->
// older than the tile's nt stores (in-order vmcnt retirement keeps the
// load-wait at vmcnt(4), never draining the store stream). Ps is per-wave
// (wave-internal lgkm ordering, no barrier). LDS 44KB -> 3 blocks/CU
// (12 waves/CU; R9's dbuf failure was 6 waves/CU at 128-thread blocks).
// ---------------------------------------------------------------------------
__global__ __launch_bounds__(256) void attn_kernel(
    const unsigned short* __restrict__ qh, const unsigned short* __restrict__ kh,
    const unsigned short* __restrict__ vt, float* __restrict__ attn,
    unsigned short* __restrict__ comb)
{
  __shared__ unsigned short Ks[2][64][64];    // K tile dbuf [k][d], SWZ
  __shared__ unsigned short Vs[2][64][64];    // V^T tile dbuf [d][k], SWZ
  __shared__ unsigned short Ps[4][16][88];    // per-wave P tile [q][k], pad 88

  const int tid = threadIdx.x;
  const int lane = tid & 63, w = tid >> 6;
  const int c = lane & 15, g = lane >> 4;

  // bijective chunked XCD swizzle: XCD r gets bh in [4r, 4r+4)
  const int lin = blockIdx.x;
  const int swz = (lin & 7) * 64 + (lin >> 3);
  const int bh = swz >> 4;
  const int q0 = (swz & 15) * 128;

  const unsigned short* Qb = qh + (size_t)bh * S_ * HD_;
  const unsigned short* Kb = kh + (size_t)bh * S_ * HD_;
  const unsigned short* Vb = vt + (size_t)bh * HD_ * S_;
  float* attnb = attn + (size_t)bh * S_ * S_;

  const int sr = tid >> 2;            // staging row 0..63
  const int scol = (tid & 3) * 16;    // 0,16,32,48
  const int swcol = SWZ(sr, scol);

  bf16x8 aQA[2], aQB[2];
#pragma unroll
  for (int t = 0; t < 2; ++t) {
    aQA[t] = *(const bf16x8*)(Qb + (size_t)(q0 + w * 16 + c) * HD_ + t * 32 + g * 8);
    aQB[t] = *(const bf16x8*)(Qb + (size_t)(q0 + 64 + w * 16 + c) * HD_ + t * 32 + g * 8);
  }

  const unsigned short* Kst = Kb + (size_t)sr * HD_ + scol;
  const unsigned short* Vst = Vb + (size_t)sr * S_ + scol;

  // ---- sweep 1: expsum(A); K dbuf, one barrier/tile ----
  float lA = 0.f, lB = 0.f;
  {
    ushort8 kr0 = *(const ushort8*)Kst;
    ushort8 kr1 = *(const ushort8*)(Kst + 8);
    for (int kt = 0; kt < 32; ++kt) {
      const int p = kt & 1;
      *(ushort8*)&Ks[p][sr][swcol]     = kr0;
      *(ushort8*)&Ks[p][sr][swcol + 8] = kr1;
      if (kt < 31) {
        const unsigned short* np = Kst + (size_t)(kt + 1) * 64 * HD_;
        kr0 = *(const ushort8*)np;
        kr1 = *(const ushort8*)(np + 8);
      }
      LGKM_BARRIER();
#pragma unroll
      for (int ni = 0; ni < 4; ++ni) {
        bf16x8 k0 = *(bf16x8*)&Ks[p][ni * 16 + c][SWZ(c, g * 8)];
        bf16x8 k1 = *(bf16x8*)&Ks[p][ni * 16 + c][SWZ(c, 32 + g * 8)];
        f32x4 a = (f32x4){0.f, 0.f, 0.f, 0.f};
        a = mfma16(k0, aQA[0], a);
        a = mfma16(k1, aQA[1], a);
        lA += (fexp2(a[0]) + fexp2(a[1])) + (fexp2(a[2]) + fexp2(a[3]));
      }
    }
  }
  lA += __shfl_xor(lA, 16);
  lA += __shfl_xor(lA, 32);
  const float invlA = 1.f / lA;

  // ---- sweep 2: pass-2(A) + expsum(B); K/V dbuf, one barrier/tile ----
  f32x4 ctxA[4], ctxB[4];
#pragma unroll
  for (int ni = 0; ni < 4; ++ni) {
    ctxA[ni] = (f32x4){0.f, 0.f, 0.f, 0.f};
    ctxB[ni] = (f32x4){0.f, 0.f, 0.f, 0.f};
  }

  unsigned short* psrow = &Ps[w][c][g * 4];
  float* srowA = attnb + (size_t)(q0 + w * 16 + g) * S_ + c * 4;
  float* srowB = attnb + (size_t)(q0 + 64 + w * 16 + g) * S_ + c * 4;

  {
    ushort8 kr0 = *(const ushort8*)Kst;
    ushort8 kr1 = *(const ushort8*)(Kst + 8);
    ushort8 vr0 = *(const ushort8*)Vst;
    ushort8 vr1 = *(const ushort8*)(Vst + 8);

    for (int kt = 0; kt < 32; ++kt) {
      const int p = kt & 1;
      *(ushort8*)&Ks[p][sr][swcol]     = kr0;
      *(ushort8*)&Ks[p][sr][swcol + 8] = kr1;
      *(ushort8*)&Vs[p][sr][swcol]     = vr0;
      *(ushort8*)&Vs[p][sr][swcol + 8] = vr1;
      if (kt < 31) {                   // loads older than this tile's stores
        const unsigned short* np = Kst + (size_t)(kt + 1) * 64 * HD_;
        const unsigned short* nq = Vst + (kt + 1) * 64;
        kr0 = *(const ushort8*)np;
        kr1 = *(const ushort8*)(np + 8);
        vr0 = *(const ushort8*)nq;
        vr1 = *(const ushort8*)(nq + 8);
      }
      LGKM_BARRIER();

#pragma unroll
      for (int ni = 0; ni < 4; ++ni) {
        bf16x8 k0 = *(bf16x8*)&Ks[p][ni * 16 + c][SWZ(c, g * 8)];
        bf16x8 k1 = *(bf16x8*)&Ks[p][ni * 16 + c][SWZ(c, 32 + g * 8)];
        f32x4 a = (f32x4){0.f, 0.f, 0.f, 0.f};
        a = mfma16(k0, aQA[0], a);
        a = mfma16(k1, aQA[1], a);
        ushort4v pk;
#pragma unroll
        for (int r = 0; r < 4; ++r) pk[r] = f2bf(fexp2(a[r]) * invlA);
        *(ushort4v*)(psrow + ni * 16) = pk;
        f32x4 b = (f32x4){0.f, 0.f, 0.f, 0.f};
        b = mfma16(k0, aQB[0], b);
        b = mfma16(k1, aQB[1], b);
        lB += (fexp2(b[0]) + fexp2(b[1])) + (fexp2(b[2]) + fexp2(b[3]));
      }

      bf16x8 aP[2];
#pragma unroll
      for (int t = 0; t < 2; ++t) aP[t] = *(bf16x8*)&Ps[w][c][t * 32 + g * 8];
#pragma unroll
      for (int ni = 0; ni < 4; ++ni)
#pragma unroll
        for (int t = 0; t < 2; ++t)
          ctxA[ni] = mfma16(aP[t],
                            *(bf16x8*)&Vs[p][ni * 16 + c][SWZ(c, t * 32 + g * 8)],
                            ctxA[ni]);

#pragma unroll
      for (int it = 0; it < 4; ++it) {
        ushort4v pb = *(ushort4v*)&Ps[w][it * 4 + g][c * 4];
        f32x4 pf;
#pragma unroll
        for (int r = 0; r < 4; ++r) pf[r] = bf2f(pb[r]);
        __builtin_nontemporal_store(pf, (f32x4*)(srowA + (size_t)it * 4 * S_ + kt * 64));
      }
    }
  }
  lB += __shfl_xor(lB, 16);
  lB += __shfl_xor(lB, 32);
  const float invlB = 1.f / lB;

  // ---- sweep 3: pass-2(B); K/V dbuf, one barrier/tile ----
  {
    ushort8 kr0 = *(const ushort8*)Kst;
    ushort8 kr1 = *(const ushort8*)(Kst + 8);
    ushort8 vr0 = *(const ushort8*)Vst;
    ushort8 vr1 = *(const ushort8*)(Vst + 8);

    for (int kt = 0; kt < 32; ++kt) {
      const int p = kt & 1;
      *(ushort8*)&Ks[p][sr][swcol]     = kr0;
      *(ushort8*)&Ks[p][sr][swcol + 8] = kr1;
      *(ushort8*)&Vs[p][sr][swcol]     = vr0;
      *(ushort8*)&Vs[p][sr][swcol + 8] = vr1;
      if (kt < 31) {
        const unsigned short* np = Kst + (size_t)(kt + 1) * 64 * HD_;
        const unsigned short* nq = Vst + (kt + 1) * 64;
        kr0 = *(const ushort8*)np;
        kr1 = *(const ushort8*)(np + 8);
        vr0 = *(const ushort8*)nq;
        vr1 = *(const ushort8*)(nq + 8);
      }
      LGKM_BARRIER();

#pragma unroll
      for (int ni = 0; ni < 4; ++ni) {
        bf16x8 k0 = *(bf16x8*)&Ks[p][ni * 16 + c][SWZ(c, g * 8)];
        bf16x8 k1 = *(bf16x8*)&Ks[p][ni * 16 + c][SWZ(c, 32 + g * 8)];
        f32x4 b = (f32x4){0.f, 0.f, 0.f, 0.f};
        b = mfma16(k0, aQB[0], b);
        b = mfma16(k1, aQB[1], b);
        ushort4v pk;
#pragma unroll
        for (int r = 0; r < 4; ++r) pk[r] = f2bf(fexp2(b[r]) * invlB);
        *(ushort4v*)(psrow + ni * 16) = pk;
      }

      bf16x8 aP[2];
#pragma unroll
      for (int t = 0; t < 2; ++t) aP[t] = *(bf16x8*)&Ps[w][c][t * 32 + g * 8];
#pragma unroll
      for (int ni = 0; ni < 4; ++ni)
#pragma unroll
        for (int t = 0; t < 2; ++t)
          ctxB[ni] = mfma16(aP[t],
                            *(bf16x8*)&Vs[p][ni * 16 + c][SWZ(c, t * 32 + g * 8)],
                            ctxB[ni]);

#pragma unroll
      for (int it = 0; it < 4; ++it) {
        ushort4v pb = *(ushort4v*)&Ps[w][it * 4 + g][c * 4];
        f32x4 pf;
#pragma unroll
        for (int r = 0; r < 4; ++r) pf[r] = bf2f(pb[r]);
        __builtin_nontemporal_store(pf, (f32x4*)(srowB + (size_t)it * 4 * S_ + kt * 64));
      }
    }
  }

  const int b = bh >> 4, h = bh & 15;
#pragma unroll
  for (int ni = 0; ni < 4; ++ni)
#pragma unroll
    for (int r = 0; r < 4; ++r) {
      comb[(size_t)(b * S_ + q0 + w * 16 + g * 4 + r) * D_ + h * 64 + ni * 16 + c] =
          f2bf(ctxA[ni][r]);
      comb[(size_t)(b * S_ + q0 + 64 + w * 16 + g * 4 + r) * D_ + h * 64 + ni * 16 + c] =
          f2bf(ctxB[ni][r]);
    }
}

// ---------------------------------------------------------------------------
// Kernel C: output projection, m97-style bf16 GEMM (A=comb, B=wob), f32 out.
// ---------------------------------------------------------------------------
__global__ __launch_bounds__(256) void out_proj_kernel(
    const unsigned short* __restrict__ comb, const unsigned short* __restrict__ wob,
    float* __restrict__ out)
{
  __shared__ unsigned short As[128 * 32];
  __shared__ unsigned short Bs[128 * 32];

  const int lin = blockIdx.x + 8 * blockIdx.y;
  const int swz = (lin & 7) * 32 + (lin >> 3);
  const int bx = swz & 7, by = swz >> 3;

  const int tid = threadIdx.x;
  const int lane = tid & 63, w = tid >> 6;
  const int c = lane & 15, g = lane >> 4;
  const int wr = w >> 1, wc = w & 1;
  const int m0 = by * 128, n0 = bx * 128;

  const int arow = 2 * w * 16 + (lane >> 2);
  const int cs = (lane & 3) ^ ((lane >> 2) & 3);
  const unsigned short* Asrc0 = comb + (size_t)(m0 + arow) * D_ + cs * 8;
  const unsigned short* Asrc1 = Asrc0 + (size_t)16 * D_;
  const unsigned short* Bsrc0 = wob + (size_t)(n0 + arow) * D_ + cs * 8;
  const unsigned short* Bsrc1 = Bsrc0 + (size_t)16 * D_;
  unsigned short* Adst0 = &As[(2 * w) * 16 * 32];
  unsigned short* Adst1 = &As[(2 * w + 1) * 16 * 32];
  unsigned short* Bdst0 = &Bs[(2 * w) * 16 * 32];
  unsigned short* Bdst1 = &Bs[(2 * w + 1) * 16 * 32];

  f32x4 acc[4][4];
#pragma unroll
  for (int i = 0; i < 4; ++i)
#pragma unroll
    for (int j = 0; j < 4; ++j) acc[i][j] = (f32x4){0.f, 0.f, 0.f, 0.f};

  for (int kt = 0; kt < 32; ++kt) {
    gload16(Asrc0 + kt * 32, Adst0);
    gload16(Asrc1 + kt * 32, Adst1);
    gload16(Bsrc0 + kt * 32, Bdst0);
    gload16(Bsrc1 + kt * 32, Bdst1);
    __syncthreads();

    bf16x8 af[4], bfr[4];
#pragma unroll
    for (int i = 0; i < 4; ++i) {
      const int row = wr * 64 + i * 16 + c;
      af[i] = *(bf16x8*)&As[row * 32 + 8 * (g ^ (c & 3))];
    }
#pragma unroll
    for (int i = 0; i < 4; ++i) {
      const int row = wc * 64 + i * 16 + c;
      bfr[i] = *(bf16x8*)&Bs[row * 32 + 8 * (g ^ (c & 3))];
    }
#pragma unroll
    for (int mi = 0; mi < 4; ++mi)
#pragma unroll
      for (int ni = 0; ni < 4; ++ni)
        acc[mi][ni] = mfma16(af[mi], bfr[ni], acc[mi][ni]);
    __syncthreads();
  }

#pragma unroll
  for (int mi = 0; mi < 4; ++mi)
#pragma unroll
    for (int ni = 0; ni < 4; ++ni)
#pragma unroll
      for (int r = 0; r < 4; ++r) {
        const int m = m0 + wr * 64 + mi * 16 + g * 4 + r;
        const int n = n0 + wc * 64 + ni * 16 + c;
        out[(size_t)m * D_ + n] = acc[mi][ni][r];
      }
}

// ---------------------------------------------------------------------------
extern "C" void kernel_launch(void* const* d_in, const int* in_sizes, int n_in,
                              void* d_out, int out_size, void* d_ws, size_t ws_size,
                              hipStream_t stream)
{
  const float* q  = (const float*)d_in[0];
  const float* k  = (const float*)d_in[1];
  const float* v  = (const float*)d_in[2];
  const float* wq = (const float*)d_in[3];
  const float* wk = (const float*)d_in[4];
  const float* wv = (const float*)d_in[5];
  const float* wo = (const float*)d_in[6];

  float* out  = (float*)d_out;
  float* attn = out + (size_t)B_ * S_ * D_;   // tuple order: (out, attn)

  const size_t NE = (size_t)B_ * S_ * D_;     // 4M elems
  const size_t M1 = (size_t)D_ * D_;          // 1M elems

  // bf16 scratch inside the attn region (dead until attn_kernel overwrites):
  unsigned short* scr = (unsigned short*)attn;
  unsigned short* xq  = scr;            // 4M
  unsigned short* xk  = xq + NE;        // 4M
  unsigned short* xv  = xk + NE;        // 4M
  unsigned short* wqb = xv + NE;        // 1M
  unsigned short* wkb = wqb + M1;       // 1M
  unsigned short* wvb = wkb + M1;       // 1M

  // workspace: qh,kh,vt,comb (32MB) + wob (2MB -- must survive attn_kernel)
  unsigned short* qh   = (unsigned short*)d_ws;
  unsigned short* kh   = qh + NE;
  unsigned short* vt   = kh + NE;
  unsigned short* comb = vt + NE;
  unsigned short* wob  = comb + NE;

  cast_kernel<<<dim3(8192), dim3(256), 0, stream>>>(
      q, k, v, wq, wk, wv, wo, xq, xk, xv, wqb, wkb, wvb, wob);
  proj_qkv_kernel<<<dim3(8, 32, 3), dim3(256), 0, stream>>>(
      xq, xk, xv, wqb, wkb, wvb, qh, kh, vt);
  attn_kernel<<<dim3(512), dim3(256), 0, stream>>>(qh, kh, vt, attn, comb);
  out_proj_kernel<<<dim3(8, 32), dim3(256), 0, stream>>>(comb, wob, out);
}

// Round 17
// 209.537 us; speedup vs baseline: 1.0184x; 1.0184x over previous
//
#include <hip/hip_runtime.h>
#include <hip/hip_bf16.h>
#include <cstdint>

#define B_ 2
#define S_ 2048
#define D_ 1024
#define H_ 16
#define HD_ 64

#define SCALE_LOG2 0.18033688011112042f   // (1/8) * log2(e), folded into wq cast

typedef __attribute__((ext_vector_type(8))) __bf16 bf16x8;
typedef __attribute__((ext_vector_type(8))) unsigned short ushort8;
typedef __attribute__((ext_vector_type(4))) unsigned short ushort4v;
typedef __attribute__((ext_vector_type(4))) float f32x4;

__device__ __forceinline__ unsigned short f2bf(float f) {
  __bf16 h = (__bf16)f;                       // native v_cvt (RNE)
  return __builtin_bit_cast(unsigned short, h);
}

__device__ __forceinline__ float bf2f(unsigned short u) {
  union { unsigned int i; float f; } v; v.i = ((unsigned int)u) << 16; return v.f;
}

__device__ __forceinline__ float fexp2(float x) {
#if __has_builtin(__builtin_amdgcn_exp2f)
  return __builtin_amdgcn_exp2f(x);           // raw v_exp_f32
#else
  return exp2f(x);
#endif
}

__device__ __forceinline__ f32x4 mfma16(bf16x8 a, bf16x8 b, f32x4 c) {
  return __builtin_amdgcn_mfma_f32_16x16x32_bf16(a, b, c, 0, 0, 0);
}

// async global->LDS DMA, 16B per lane: LDS dest = wave-uniform base + lane*16
__device__ __forceinline__ void gload16(const unsigned short* g, unsigned short* l) {
  __builtin_amdgcn_global_load_lds(
      (const __attribute__((address_space(1))) unsigned int*)g,
      (__attribute__((address_space(3))) unsigned int*)l, 16, 0, 0);
}

// LDS-hazard-only barrier: does NOT drain vmcnt (attn kernel only).
#define LGKM_BARRIER()                                        \
  do {                                                        \
    asm volatile("s_waitcnt lgkmcnt(0)" ::: "memory");        \
    __builtin_amdgcn_s_barrier();                             \
  } while (0)

// 32B-granule XOR swizzle for [64][64]-short LDS tiles (keeps 16B alignment).
#define SWZ(r, sc) ((sc) ^ (((r) & 3) << 4))

// ---------------------------------------------------------------------------
// Kernel 0: f32 -> bf16 pre-cast. q,k,v,wq(*scale),wk,wv -> scratch (in the
// attn region of d_out -- dead until the attn kernel overwrites it); wo -> ws.
// ---------------------------------------------------------------------------
__global__ __launch_bounds__(256) void cast_kernel(
    const float* __restrict__ q, const float* __restrict__ k,
    const float* __restrict__ v, const float* __restrict__ wq,
    const float* __restrict__ wk, const float* __restrict__ wv,
    const float* __restrict__ wo,
    unsigned short* __restrict__ xq, unsigned short* __restrict__ xk,
    unsigned short* __restrict__ xv, unsigned short* __restrict__ wqb,
    unsigned short* __restrict__ wkb, unsigned short* __restrict__ wvb,
    unsigned short* __restrict__ wob)
{
  const size_t M4 = (size_t)4 << 20, M1 = (size_t)1 << 20;
  size_t i = ((size_t)blockIdx.x * 256 + threadIdx.x) * 8;
  const float* src; unsigned short* dst; float sc = 1.f; size_t off;
  if (i < M4)                 { src = q;  dst = xq;  off = i; }
  else if (i < 2 * M4)        { src = k;  dst = xk;  off = i - M4; }
  else if (i < 3 * M4)        { src = v;  dst = xv;  off = i - 2 * M4; }
  else if (i < 3 * M4 + M1)   { src = wq; dst = wqb; off = i - 3 * M4; sc = SCALE_LOG2; }
  else if (i < 3 * M4 + 2*M1) { src = wk; dst = wkb; off = i - 3 * M4 - M1; }
  else if (i < 3 * M4 + 3*M1) { src = wv; dst = wvb; off = i - 3 * M4 - 2 * M1; }
  else                        { src = wo; dst = wob; off = i - 3 * M4 - 3 * M1; }
  f32x4 a = *(const f32x4*)(src + off);
  f32x4 b = *(const f32x4*)(src + off + 4);
  ushort8 o;
#pragma unroll
  for (int r = 0; r < 4; ++r) { o[r] = f2bf(a[r] * sc); o[4 + r] = f2bf(b[r] * sc); }
  *(ushort8*)(dst + off) = o;
}

// ---------------------------------------------------------------------------
// Kernel A: QKV projections, bf16 NT GEMM with global_load_lds (m97 recipe).
// C[m][n] = sum_k X[m][k] * W[n][k].  128x128 tile, BK=32, 4 waves 64x64.
// Swizzle (rule #21): linear LDS dest + inverse-permuted GLOBAL src slot
// (cs = (l&3) ^ ((l>>2)&3)) + XOR on read (slot = g ^ (row&3)).
// ---------------------------------------------------------------------------
__global__ __launch_bounds__(256) void proj_qkv_kernel(
    const unsigned short* __restrict__ xq, const unsigned short* __restrict__ xk,
    const unsigned short* __restrict__ xv, const unsigned short* __restrict__ wqb,
    const unsigned short* __restrict__ wkb, const unsigned short* __restrict__ wvb,
    unsigned short* __restrict__ qh, unsigned short* __restrict__ kh,
    unsigned short* __restrict__ vt)
{
  __shared__ unsigned short As[128 * 32];   // linear, row = 32 bf16 (64B)
  __shared__ unsigned short Bs[128 * 32];

  const int z = blockIdx.z;
  const unsigned short* X = (z == 0) ? xq : (z == 1) ? xk : xv;
  const unsigned short* W = (z == 0) ? wqb : (z == 1) ? wkb : wvb;
  unsigned short* dst = (z == 0) ? qh : (z == 1) ? kh : vt;

  const int lin = blockIdx.x + 8 * blockIdx.y;
  const int swz = (lin & 7) * 32 + (lin >> 3);
  const int bx = swz & 7, by = swz >> 3;

  const int tid = threadIdx.x;
  const int lane = tid & 63, w = tid >> 6;
  const int c = lane & 15, g = lane >> 4;
  const int wr = w >> 1, wc = w & 1;               // 2x2 waves, 64x64 each
  const int m0 = by * 128, n0 = bx * 128;

  const int arow = 2 * w * 16 + (lane >> 2);
  const int cs = (lane & 3) ^ ((lane >> 2) & 3);   // inverse-permuted src slot
  const unsigned short* Asrc0 = X + (size_t)(m0 + arow) * D_ + cs * 8;
  const unsigned short* Asrc1 = Asrc0 + (size_t)16 * D_;
  const unsigned short* Bsrc0 = W + (size_t)(n0 + arow) * D_ + cs * 8;
  const unsigned short* Bsrc1 = Bsrc0 + (size_t)16 * D_;
  unsigned short* Adst0 = &As[(2 * w) * 16 * 32];
  unsigned short* Adst1 = &As[(2 * w + 1) * 16 * 32];
  unsigned short* Bdst0 = &Bs[(2 * w) * 16 * 32];
  unsigned short* Bdst1 = &Bs[(2 * w + 1) * 16 * 32];

  f32x4 acc[4][4];
#pragma unroll
  for (int i = 0; i < 4; ++i)
#pragma unroll
    for (int j = 0; j < 4; ++j) acc[i][j] = (f32x4){0.f, 0.f, 0.f, 0.f};

  for (int kt = 0; kt < 32; ++kt) {
    gload16(Asrc0 + kt * 32, Adst0);
    gload16(Asrc1 + kt * 32, Adst1);
    gload16(Bsrc0 + kt * 32, Bdst0);
    gload16(Bsrc1 + kt * 32, Bdst1);
    __syncthreads();

    bf16x8 af[4], bfr[4];
#pragma unroll
    for (int i = 0; i < 4; ++i) {
      const int row = wr * 64 + i * 16 + c;
      af[i] = *(bf16x8*)&As[row * 32 + 8 * (g ^ (c & 3))];
    }
#pragma unroll
    for (int i = 0; i < 4; ++i) {
      const int row = wc * 64 + i * 16 + c;
      bfr[i] = *(bf16x8*)&Bs[row * 32 + 8 * (g ^ (c & 3))];
    }
#pragma unroll
    for (int mi = 0; mi < 4; ++mi)
#pragma unroll
      for (int ni = 0; ni < 4; ++ni)
        acc[mi][ni] = mfma16(af[mi], bfr[ni], acc[mi][ni]);
    __syncthreads();
  }

#pragma unroll
  for (int mi = 0; mi < 4; ++mi) {
#pragma unroll
    for (int ni = 0; ni < 4; ++ni) {
      const int n = n0 + wc * 64 + ni * 16 + c;
      const int h = n >> 6, hd = n & 63;
      if (z < 2) {
#pragma unroll
        for (int r = 0; r < 4; ++r) {
          const int m = m0 + wr * 64 + mi * 16 + g * 4 + r;
          const int b = m >> 11, s = m & 2047;
          dst[((size_t)(b * H_ + h) * S_ + s) * HD_ + hd] = f2bf(acc[mi][ni][r]);
        }
      } else {
        const int m = m0 + wr * 64 + mi * 16 + g * 4;
        const int b = m >> 11, s = m & 2047;
        ushort4v pk;
#pragma unroll
        for (int r = 0; r < 4; ++r) pk[r] = f2bf(acc[mi][ni][r]);
        *(ushort4v*)&dst[((size_t)(b * H_ + h) * HD_ + hd) * S_ + s] = pk;
      }
    }
  }
}

// ---------------------------------------------------------------------------
// Kernel B: attention (R14/R15 best config): 3-sweep A/B fusion, swapped
// QK^T, no-max softmax, single-buffered SWZ K/V tiles (27KB LDS -> 5
// blocks/CU), Ps->coalesced nt f32x4 stores, lgkm-only barriers.
// ---------------------------------------------------------------------------
__global__ __launch_bounds__(256) void attn_kernel(
    const unsigned short* __restrict__ qh, const unsigned short* __restrict__ kh,
    const unsigned short* __restrict__ vt, float* __restrict__ attn,
    unsigned short* __restrict__ comb)
{
  __shared__ unsigned short Ks[64][64];       // K tile [k][d], SWZ-swizzled
  __shared__ unsigned short Vs[64][64];       // V^T tile [d][k], SWZ-swizzled
  __shared__ unsigned short Ps[4][16][88];    // per-wave P tile [q][k], pad 88

  const int tid = threadIdx.x;
  const int lane = tid & 63, w = tid >> 6;
  const int c = lane & 15, g = lane >> 4;

  // bijective chunked XCD swizzle: XCD r gets bh in [4r, 4r+4)
  const int lin = blockIdx.x;
  const int swz = (lin & 7) * 64 + (lin >> 3);
  const int bh = swz >> 4;
  const int q0 = (swz & 15) * 128;

  const unsigned short* Qb = qh + (size_t)bh * S_ * HD_;
  const unsigned short* Kb = kh + (size_t)bh * S_ * HD_;
  const unsigned short* Vb = vt + (size_t)bh * HD_ * S_;
  float* attnb = attn + (size_t)bh * S_ * S_;

  const int sr = tid >> 2;            // staging row 0..63
  const int scol = (tid & 3) * 16;    // 0,16,32,48
  const int swcol = SWZ(sr, scol);

  bf16x8 aQA[2], aQB[2];
#pragma unroll
  for (int t = 0; t < 2; ++t) {
    aQA[t] = *(const bf16x8*)(Qb + (size_t)(q0 + w * 16 + c) * HD_ + t * 32 + g * 8);
    aQB[t] = *(const bf16x8*)(Qb + (size_t)(q0 + 64 + w * 16 + c) * HD_ + t * 32 + g * 8);
  }

  const unsigned short* Kst = Kb + (size_t)sr * HD_ + scol;
  const unsigned short* Vst = Vb + (size_t)sr * S_ + scol;

  // ---- sweep 1: expsum(A) ----
  float lA = 0.f, lB = 0.f;
  {
    ushort8 kr0 = *(const ushort8*)Kst;
    ushort8 kr1 = *(const ushort8*)(Kst + 8);
    for (int kt = 0; kt < 32; ++kt) {
      *(ushort8*)&Ks[sr][swcol]     = kr0;
      *(ushort8*)&Ks[sr][swcol + 8] = kr1;
      LGKM_BARRIER();
      if (kt < 31) {
        const unsigned short* p = Kst + (size_t)(kt + 1) * 64 * HD_;
        kr0 = *(const ushort8*)p;
        kr1 = *(const ushort8*)(p + 8);
      }
#pragma unroll
      for (int ni = 0; ni < 4; ++ni) {
        bf16x8 k0 = *(bf16x8*)&Ks[ni * 16 + c][SWZ(c, g * 8)];
        bf16x8 k1 = *(bf16x8*)&Ks[ni * 16 + c][SWZ(c, 32 + g * 8)];
        f32x4 a = (f32x4){0.f, 0.f, 0.f, 0.f};
        a = mfma16(k0, aQA[0], a);
        a = mfma16(k1, aQA[1], a);
        lA += (fexp2(a[0]) + fexp2(a[1])) + (fexp2(a[2]) + fexp2(a[3]));
      }
      LGKM_BARRIER();
    }
  }
  lA += __shfl_xor(lA, 16);
  lA += __shfl_xor(lA, 32);
  const float invlA = 1.f / lA;

  // ---- sweep 2: pass-2(A) + expsum(B) ----
  f32x4 ctxA[4], ctxB[4];
#pragma unroll
  for (int ni = 0; ni < 4; ++ni) {
    ctxA[ni] = (f32x4){0.f, 0.f, 0.f, 0.f};
    ctxB[ni] = (f32x4){0.f, 0.f, 0.f, 0.f};
  }

  unsigned short* psrow = &Ps[w][c][g * 4];
  float* srowA = attnb + (size_t)(q0 + w * 16 + g) * S_ + c * 4;
  float* srowB = attnb + (size_t)(q0 + 64 + w * 16 + g) * S_ + c * 4;

  {
    ushort8 kr0 = *(const ushort8*)Kst;
    ushort8 kr1 = *(const ushort8*)(Kst + 8);
    ushort8 vr0 = *(const ushort8*)Vst;
    ushort8 vr1 = *(const ushort8*)(Vst + 8);

    for (int kt = 0; kt < 32; ++kt) {
      *(ushort8*)&Ks[sr][swcol]     = kr0;
      *(ushort8*)&Ks[sr][swcol + 8] = kr1;
      *(ushort8*)&Vs[sr][swcol]     = vr0;
      *(ushort8*)&Vs[sr][swcol + 8] = vr1;
      LGKM_BARRIER();
      if (kt < 31) {                     // prefetch BEFORE this tile's stores
        const unsigned short* p = Kst + (size_t)(kt + 1) * 64 * HD_;
        const unsigned short* q = Vst + (kt + 1) * 64;
        kr0 = *(const ushort8*)p;
        kr1 = *(const ushort8*)(p + 8);
        vr0 = *(const ushort8*)q;
        vr1 = *(const ushort8*)(q + 8);
      }

#pragma unroll
      for (int ni = 0; ni < 4; ++ni) {
        bf16x8 k0 = *(bf16x8*)&Ks[ni * 16 + c][SWZ(c, g * 8)];
        bf16x8 k1 = *(bf16x8*)&Ks[ni * 16 + c][SWZ(c, 32 + g * 8)];
        f32x4 a = (f32x4){0.f, 0.f, 0.f, 0.f};
        a = mfma16(k0, aQA[0], a);
        a = mfma16(k1, aQA[1], a);
        ushort4v pk;
#pragma unroll
        for (int r = 0; r < 4; ++r) pk[r] = f2bf(fexp2(a[r]) * invlA);
        *(ushort4v*)(psrow + ni * 16) = pk;
        f32x4 b = (f32x4){0.f, 0.f, 0.f, 0.f};
        b = mfma16(k0, aQB[0], b);
        b = mfma16(k1, aQB[1], b);
        lB += (fexp2(b[0]) + fexp2(b[1])) + (fexp2(b[2]) + fexp2(b[3]));
      }

      bf16x8 aP[2];
#pragma unroll
      for (int t = 0; t < 2; ++t) aP[t] = *(bf16x8*)&Ps[w][c][t * 32 + g * 8];
#pragma unroll
      for (int ni = 0; ni < 4; ++ni)
#pragma unroll
        for (int t = 0; t < 2; ++t)
          ctxA[ni] = mfma16(aP[t],
                            *(bf16x8*)&Vs[ni * 16 + c][SWZ(c, t * 32 + g * 8)],
                            ctxA[ni]);

#pragma unroll
      for (int it = 0; it < 4; ++it) {
        ushort4v pb = *(ushort4v*)&Ps[w][it * 4 + g][c * 4];
        f32x4 pf;
#pragma unroll
        for (int r = 0; r < 4; ++r) pf[r] = bf2f(pb[r]);
        __builtin_nontemporal_store(pf, (f32x4*)(srowA + (size_t)it * 4 * S_ + kt * 64));
      }
      LGKM_BARRIER();
    }
  }
  lB += __shfl_xor(lB, 16);
  lB += __shfl_xor(lB, 32);
  const float invlB = 1.f / lB;

  // ---- sweep 3: pass-2(B) ----
  {
    ushort8 kr0 = *(const ushort8*)Kst;
    ushort8 kr1 = *(const ushort8*)(Kst + 8);
    ushort8 vr0 = *(const ushort8*)Vst;
    ushort8 vr1 = *(const ushort8*)(Vst + 8);

    for (int kt = 0; kt < 32; ++kt) {
      *(ushort8*)&Ks[sr][swcol]     = kr0;
      *(ushort8*)&Ks[sr][swcol + 8] = kr1;
      *(ushort8*)&Vs[sr][swcol]     = vr0;
      *(ushort8*)&Vs[sr][swcol + 8] = vr1;
      LGKM_BARRIER();
      if (kt < 31) {
        const unsigned short* p = Kst + (size_t)(kt + 1) * 64 * HD_;
        const unsigned short* q = Vst + (kt + 1) * 64;
        kr0 = *(const ushort8*)p;
        kr1 = *(const ushort8*)(p + 8);
        vr0 = *(const ushort8*)q;
        vr1 = *(const ushort8*)(q + 8);
      }

#pragma unroll
      for (int ni = 0; ni < 4; ++ni) {
        bf16x8 k0 = *(bf16x8*)&Ks[ni * 16 + c][SWZ(c, g * 8)];
        bf16x8 k1 = *(bf16x8*)&Ks[ni * 16 + c][SWZ(c, 32 + g * 8)];
        f32x4 b = (f32x4){0.f, 0.f, 0.f, 0.f};
        b = mfma16(k0, aQB[0], b);
        b = mfma16(k1, aQB[1], b);
        ushort4v pk;
#pragma unroll
        for (int r = 0; r < 4; ++r) pk[r] = f2bf(fexp2(b[r]) * invlB);
        *(ushort4v*)(psrow + ni * 16) = pk;
      }

      bf16x8 aP[2];
#pragma unroll
      for (int t = 0; t < 2; ++t) aP[t] = *(bf16x8*)&Ps[w][c][t * 32 + g * 8];
#pragma unroll
      for (int ni = 0; ni < 4; ++ni)
#pragma unroll
        for (int t = 0; t < 2; ++t)
          ctxB[ni] = mfma16(aP[t],
                            *(bf16x8*)&Vs[ni * 16 + c][SWZ(c, t * 32 + g * 8)],
                            ctxB[ni]);

#pragma unroll
      for (int it = 0; it < 4; ++it) {
        ushort4v pb = *(ushort4v*)&Ps[w][it * 4 + g][c * 4];
        f32x4 pf;
#pragma unroll
        for (int r = 0; r < 4; ++r) pf[r] = bf2f(pb[r]);
        __builtin_nontemporal_store(pf, (f32x4*)(srowB + (size_t)it * 4 * S_ + kt * 64));
      }
      LGKM_BARRIER();
    }
  }

  const int b = bh >> 4, h = bh & 15;
#pragma unroll
  for (int ni = 0; ni < 4; ++ni)
#pragma unroll
    for (int r = 0; r < 4; ++r) {
      comb[(size_t)(b * S_ + q0 + w * 16 + g * 4 + r) * D_ + h * 64 + ni * 16 + c] =
          f2bf(ctxA[ni][r]);
      comb[(size_t)(b * S_ + q0 + 64 + w * 16 + g * 4 + r) * D_ + h * 64 + ni * 16 + c] =
          f2bf(ctxB[ni][r]);
    }
}

// ---------------------------------------------------------------------------
// Kernel C: output projection, m97-style bf16 GEMM (A=comb, B=wob), f32 out.
// ---------------------------------------------------------------------------
__global__ __launch_bounds__(256) void out_proj_kernel(
    const unsigned short* __restrict__ comb, const unsigned short* __restrict__ wob,
    float* __restrict__ out)
{
  __shared__ unsigned short As[128 * 32];
  __shared__ unsigned short Bs[128 * 32];

  const int lin = blockIdx.x + 8 * blockIdx.y;
  const int swz = (lin & 7) * 32 + (lin >> 3);
  const int bx = swz & 7, by = swz >> 3;

  const int tid = threadIdx.x;
  const int lane = tid & 63, w = tid >> 6;
  const int c = lane & 15, g = lane >> 4;
  const int wr = w >> 1, wc = w & 1;
  const int m0 = by * 128, n0 = bx * 128;

  const int arow = 2 * w * 16 + (lane >> 2);
  const int cs = (lane & 3) ^ ((lane >> 2) & 3);
  const unsigned short* Asrc0 = comb + (size_t)(m0 + arow) * D_ + cs * 8;
  const unsigned short* Asrc1 = Asrc0 + (size_t)16 * D_;
  const unsigned short* Bsrc0 = wob + (size_t)(n0 + arow) * D_ + cs * 8;
  const unsigned short* Bsrc1 = Bsrc0 + (size_t)16 * D_;
  unsigned short* Adst0 = &As[(2 * w) * 16 * 32];
  unsigned short* Adst1 = &As[(2 * w + 1) * 16 * 32];
  unsigned short* Bdst0 = &Bs[(2 * w) * 16 * 32];
  unsigned short* Bdst1 = &Bs[(2 * w + 1) * 16 * 32];

  f32x4 acc[4][4];
#pragma unroll
  for (int i = 0; i < 4; ++i)
#pragma unroll
    for (int j = 0; j < 4; ++j) acc[i][j] = (f32x4){0.f, 0.f, 0.f, 0.f};

  for (int kt = 0; kt < 32; ++kt) {
    gload16(Asrc0 + kt * 32, Adst0);
    gload16(Asrc1 + kt * 32, Adst1);
    gload16(Bsrc0 + kt * 32, Bdst0);
    gload16(Bsrc1 + kt * 32, Bdst1);
    __syncthreads();

    bf16x8 af[4], bfr[4];
#pragma unroll
    for (int i = 0; i < 4; ++i) {
      const int row = wr * 64 + i * 16 + c;
      af[i] = *(bf16x8*)&As[row * 32 + 8 * (g ^ (c & 3))];
    }
#pragma unroll
    for (int i = 0; i < 4; ++i) {
      const int row = wc * 64 + i * 16 + c;
      bfr[i] = *(bf16x8*)&Bs[row * 32 + 8 * (g ^ (c & 3))];
    }
#pragma unroll
    for (int mi = 0; mi < 4; ++mi)
#pragma unroll
      for (int ni = 0; ni < 4; ++ni)
        acc[mi][ni] = mfma16(af[mi], bfr[ni], acc[mi][ni]);
    __syncthreads();
  }

#pragma unroll
  for (int mi = 0; mi < 4; ++mi)
#pragma unroll
    for (int ni = 0; ni < 4; ++ni)
#pragma unroll
      for (int r = 0; r < 4; ++r) {
        const int m = m0 + wr * 64 + mi * 16 + g * 4 + r;
        const int n = n0 + wc * 64 + ni * 16 + c;
        out[(size_t)m * D_ + n] = acc[mi][ni][r];
      }
}

// ---------------------------------------------------------------------------
extern "C" void kernel_launch(void* const* d_in, const int* in_sizes, int n_in,
                              void* d_out, int out_size, void* d_ws, size_t ws_size,
                              hipStream_t stream)
{
  const float* q  = (const float*)d_in[0];
  const float* k  = (const float*)d_in[1];
  const float* v  = (const float*)d_in[2];
  const float* wq = (const float*)d_in[3];
  const float* wk = (const float*)d_in[4];
  const float* wv = (const float*)d_in[5];
  const float* wo = (const float*)d_in[6];

  float* out  = (float*)d_out;
  float* attn = out + (size_t)B_ * S_ * D_;   // tuple order: (out, attn)

  const size_t NE = (size_t)B_ * S_ * D_;     // 4M elems
  const size_t M1 = (size_t)D_ * D_;          // 1M elems

  // bf16 scratch inside the attn region (dead until attn_kernel overwrites):
  unsigned short* scr = (unsigned short*)attn;
  unsigned short* xq  = scr;            // 4M
  unsigned short* xk  = xq + NE;        // 4M
  unsigned short* xv  = xk + NE;        // 4M
  unsigned short* wqb = xv + NE;        // 1M
  unsigned short* wkb = wqb + M1;       // 1M
  unsigned short* wvb = wkb + M1;       // 1M

  // workspace: qh,kh,vt,comb (32MB) + wob (2MB -- must survive attn_kernel)
  unsigned short* qh   = (unsigned short*)d_ws;
  unsigned short* kh   = qh + NE;
  unsigned short* vt   = kh + NE;
  unsigned short* comb = vt + NE;
  unsigned short* wob  = comb + NE;

  cast_kernel<<<dim3(8192), dim3(256), 0, stream>>>(
      q, k, v, wq, wk, wv, wo, xq, xk, xv, wqb, wkb, wvb, wob);
  proj_qkv_kernel<<<dim3(8, 32, 3), dim3(256), 0, stream>>>(
      xq, xk, xv, wqb, wkb, wvb, qh, kh, vt);
  attn_kernel<<<dim3(512), dim3(256), 0, stream>>>(qh, kh, vt, attn, comb);
  out_proj_kernel<<<dim3(8, 32), dim3(256), 0, stream>>>(comb, wob, out);
}